// Round 7
// baseline (132.516 us; speedup 1.0000x reference)
//
#include <hip/hip_runtime.h>

// 10-qubit batched statevector simulator.
// One wave (64 lanes) per sample; 4 waves/block; 4 samples per wave
// sequentially => 16 samples/block, grid = B/16 = 2048 blocks = exactly
// 8 blocks/CU resident (one occupancy round, setup amortized 16x).
// Amp index bits: 0..5 = lane bits, 6..8 = k-index of v2f arrays,
// 9 = element (x/y) of each v2f. Qubit q (MSB-first) is amp bit p = 9-q.
//
// Round-7 changes vs round-6 (VALUBusy 83%, Occupancy 58%):
//  (a) block-level batch trig: all 160 per-sample sincos computed by setup
//      threads into LDS; hot loop reads broadcast ds_read_b64.
//  (b) per-lane diag phase tables (D_phi/D_omega lane part, weights-only).
//  (c) per-lane selected layer-0 row table (kills cndmasks in the fold).
//  (d) per-sample u-vector table for the reg-bit product tree.
//  (e) grid 8192x(1 sample/wave) -> 2048x(4 samples/wave).

namespace {

constexpr int NQB = 10;
constexpr int SPB = 16;    // samples per block
constexpr int SPW = 4;     // samples per wave

typedef float v2f __attribute__((ext_vector_type(2)));

template<int CTRL>
__device__ __forceinline__ float dppf(float x) {
  return __uint_as_float((unsigned)__builtin_amdgcn_update_dpp(
      0, (int)__float_as_uint(x), CTRL, 0xF, 0xF, true));
}

// Partner value x[lane ^ (1<<P)].
// P=0,1,3: single DPP. P=2: ds_swizzle XOR4. P=4: ds_swizzle XOR16.
// P=5: ds_bpermute (addr bpa = (lane^32)<<2).
template<int P>
__device__ __forceinline__ float xorf(float x, int bpa) {
  if constexpr (P == 0) {
    return dppf<0xB1>(x);                       // quad_perm [1,0,3,2] = XOR1
  } else if constexpr (P == 1) {
    return dppf<0x4E>(x);                       // quad_perm [2,3,0,1] = XOR2
  } else if constexpr (P == 2) {
    return __uint_as_float((unsigned)__builtin_amdgcn_ds_swizzle(
        (int)__float_as_uint(x), 0x101F));      // bitmode xor=4
  } else if constexpr (P == 3) {
    return dppf<0x128>(x);                      // row_ror:8 == XOR8 within row16
  } else if constexpr (P == 4) {
    return __uint_as_float((unsigned)__builtin_amdgcn_ds_swizzle(
        (int)__float_as_uint(x), 0x401F));      // bitmode xor=16
  } else {
    return __uint_as_float((unsigned)__builtin_amdgcn_ds_bpermute(
        bpa, (int)__float_as_uint(x)));
  }
}

template<int P>
__device__ __forceinline__ v2f partner2(v2f v, int bpa) {
  v2f r;
  r.x = xorf<P>(v.x, bpa);
  r.y = xorf<P>(v.y, bpa);
  return r;
}

__device__ __forceinline__ float fsin_rev(float rev) {
#if __has_builtin(__builtin_amdgcn_sinf)
  return __builtin_amdgcn_sinf(rev);
#else
  return __sinf(rev * 6.2831853071795864769f);
#endif
}
__device__ __forceinline__ float fcos_rev(float rev) {
#if __has_builtin(__builtin_amdgcn_cosf)
  return __builtin_amdgcn_cosf(rev);
#else
  return __cosf(rev * 6.2831853071795864769f);
#endif
}

__device__ __forceinline__ float clamp01(float x) {
#if __has_builtin(__builtin_amdgcn_fmed3f)
  return __builtin_amdgcn_fmed3f(x, 0.0f, 1.0f);
#else
  return fminf(fmaxf(x, 0.0f), 1.0f);
#endif
}

__device__ __forceinline__ void cmul(float& r, float& i, float br, float bi) {
  const float tr = r * br - i * bi;
  i = r * bi + i * br;
  r = tr;
}

// ---- diagonal layer: S[k] *= (zr + i zi) * RA[k][axis] ----
__device__ __forceinline__ void apply_diag(v2f (&Sr)[8], v2f (&Si)[8],
                                           float zr, float zi, const float (*tab)[4]) {
#pragma unroll
  for (int k = 0; k < 8; ++k) {
    const float4 t4 = *(const float4*)&tab[k][0];
    const v2f Rr = {t4.x, t4.y}, Ri = {t4.z, t4.w};
    const v2f tr = zr*Sr[k] - zi*Si[k];
    const v2f ti = zi*Sr[k] + zr*Si[k];
    Sr[k] = tr*Rr - ti*Ri;
    Si[k] = tr*Ri + ti*Rr;
  }
}

// ---- real RY gates (c = cos(th/2), s = sin(th/2)) ----

__device__ __forceinline__ void ry_axis(v2f (&Sr)[8], v2f (&Si)[8], float c, float s) {
  const v2f sv = {-s, s};
#pragma unroll
  for (int k = 0; k < 8; ++k) {
    const v2f ar = Sr[k], ai = Si[k];
    Sr[k] = c*ar + sv*ar.yx;
    Si[k] = c*ai + sv*ai.yx;
  }
}

template<int J>
__device__ __forceinline__ void ry_reg(v2f (&Sr)[8], v2f (&Si)[8], float c, float s) {
#pragma unroll
  for (int k0 = 0; k0 < 8; ++k0) {
    if (k0 & J) continue;
    const int k1 = k0 | J;
    const v2f a0r=Sr[k0], a0i=Si[k0], a1r=Sr[k1], a1i=Si[k1];
    Sr[k0] = c*a0r - s*a1r;  Si[k0] = c*a0i - s*a1i;
    Sr[k1] = s*a0r + c*a1r;  Si[k1] = s*a0i + c*a1i;
  }
}

template<int P>
__device__ __forceinline__ void ry_lane(v2f (&Sr)[8], v2f (&Si)[8], float c, float s,
                                        int lane, int bpa) {
  const float ss = ((lane >> P) & 1) ? s : -s;
#pragma unroll
  for (int k = 0; k < 8; ++k) {
    const v2f pr = partner2<P>(Sr[k], bpa), pi = partner2<P>(Si[k], bpa);
    Sr[k] = c*Sr[k] + ss*pr;
    Si[k] = c*Si[k] + ss*pi;
  }
}

// ---- CRY gates (real c = cos(th/2), s = sin(th/2); control==1 applies RY) ----

template<int CB, int J>
__device__ __forceinline__ void cry_reg_reg(v2f (&Sr)[8], v2f (&Si)[8], float c, float s) {
#pragma unroll
  for (int k0 = 0; k0 < 8; ++k0) {
    if ((k0 & J) || !(k0 & CB)) continue;
    const int k1 = k0 | J;
    const v2f a0r=Sr[k0], a0i=Si[k0], a1r=Sr[k1], a1i=Si[k1];
    Sr[k0] = c*a0r - s*a1r;  Si[k0] = c*a0i - s*a1i;
    Sr[k1] = s*a0r + c*a1r;  Si[k1] = s*a0i + c*a1i;
  }
}

// control on packing axis (bit 9), target k-bit 4 (amp bit 8)
__device__ __forceinline__ void cry_axisctrl(v2f (&Sr)[8], v2f (&Si)[8], float c, float s) {
  const v2f cv = {1.0f, c}, sv = {0.0f, s};
#pragma unroll
  for (int k0 = 0; k0 < 4; ++k0) {
    const int k1 = k0 + 4;
    const v2f a0r=Sr[k0], a0i=Si[k0], a1r=Sr[k1], a1i=Si[k1];
    Sr[k0] = cv*a0r - sv*a1r;  Si[k0] = cv*a0i - sv*a1i;
    Sr[k1] = sv*a0r + cv*a1r;  Si[k1] = sv*a0i + cv*a1i;
  }
}

// control k-bit 1 (amp bit 6), target lane bit 5
__device__ __forceinline__ void cry_k0ctrl_lane5(v2f (&Sr)[8], v2f (&Si)[8],
                                                 float c, float s, int lane, int bpa) {
  const float ss = ((lane >> 5) & 1) ? s : -s;
#pragma unroll
  for (int k = 1; k < 8; k += 2) {
    const v2f pr = partner2<5>(Sr[k], bpa), pi = partner2<5>(Si[k], bpa);
    Sr[k] = c*Sr[k] + ss*pr;
    Si[k] = c*Si[k] + ss*pi;
  }
}

template<int PC, int PT>
__device__ __forceinline__ void cry_lane_lane(v2f (&Sr)[8], v2f (&Si)[8],
                                              float c, float s, int lane, int bpa) {
  const bool ctrl = (lane >> PC) & 1;
  const float ce = ctrl ? c : 1.0f;
  const float se = ctrl ? s : 0.0f;
  const float ss = ((lane >> PT) & 1) ? se : -se;
#pragma unroll
  for (int k = 0; k < 8; ++k) {
    const v2f pr = partner2<PT>(Sr[k], bpa), pi = partner2<PT>(Si[k], bpa);
    Sr[k] = ce*Sr[k] + ss*pr;
    Si[k] = ce*Si[k] + ss*pi;
  }
}

// control lane bit 0, target packing axis (bit 9)
__device__ __forceinline__ void cry_lanectrl_axis(v2f (&Sr)[8], v2f (&Si)[8],
                                                  float c, float s, int lane) {
  const bool ctrl = lane & 1;
  const float ce = ctrl ? c : 1.0f;
  const float se = ctrl ? s : 0.0f;
  const v2f sv = {-se, se};
#pragma unroll
  for (int k = 0; k < 8; ++k) {
    const v2f ar = Sr[k], ai = Si[k];
    Sr[k] = ce*ar + sv*ar.yx;
    Si[k] = ce*ai + sv*ai.yx;
  }
}

} // namespace

__global__ __launch_bounds__(256)
void qlayer_kernel(const float* __restrict__ inp,   // (B, 10)
                   const float* __restrict__ wt,    // (80,)
                   float* __restrict__ out,         // (B, 10)
                   int B)
{
  __shared__ float gm[10][8];                    // layer-0 Rot matrices
  __shared__ float gc[20][2];                    // CRY cos/sin, both layers
  __shared__ float grot1[10][2];                 // layer-1 RY cos/sin
  __shared__ __align__(16) float gdphi[8][4];    // layer-1 D_phi reg/axis phases
  __shared__ __align__(16) float gdome[8][4];    // layer-1 D_omega reg/axis phases
  __shared__ float gzlane[2][64][2];             // per-lane diag phase (c,s): [0]=phi,[1]=omega
  __shared__ float gtrig[SPB][10][2];            // per-sample per-bit (fc, fs)
  __shared__ __align__(16) float growtab[6][64][4]; // selected layer-0 row, [p][lane]
  __shared__ float gutab[SPB][4][2][2];          // reg/axis u-vectors, [s][gmIdx][b][re,im]

  const int tid = threadIdx.x;
  const int base = blockIdx.x * SPB;

  // ---- setup phase 1 ----
  if (tid < 160) {
    // batch trig: sample s = tid/10, input col q = tid%10, amp bit p = 9-q
    const int s = tid / 10, q = tid - 10 * s;
    const float x = clamp01(inp[base * NQB + tid]);
    const float r = 0.25f * x;                   // (pi/2*x) in revolutions
    gtrig[s][9 - q][0] = fcos_rev(r);
    gtrig[s][9 - q][1] = fsin_rev(r);
  } else if (tid < 170) {
    // layer-0 Rot(phi, theta, omega) = RZ(omega) RY(theta) RZ(phi)
    const int q = tid - 160;
    const int w = 3 * q;
    const float phi = wt[w], th = wt[w + 1], om = wt[w + 2];
    float s, c, sa, ca, sb, cb;
    __sincosf(0.5f * th, &s, &c);
    __sincosf(0.5f * (phi + om), &sa, &ca);
    __sincosf(0.5f * (phi - om), &sb, &cb);
    gm[q][0] =  c * ca;  gm[q][1] = -c * sa;   // u00
    gm[q][2] = -s * cb;  gm[q][3] = -s * sb;   // u01
    gm[q][4] =  s * cb;  gm[q][5] = -s * sb;   // u10
    gm[q][6] =  c * ca;  gm[q][7] =  c * sa;   // u11
  } else if (tid < 190) {
    const int g = tid - 170;
    const int layer = g / 10, e = g - 10 * layer;
    const int w = layer * 40 + 30 + e;
    float s, c;
    __sincosf(0.5f * wt[w], &s, &c);
    gc[g][0] = c;
    gc[g][1] = s;
  } else if (tid < 200) {
    const int q = tid - 190;
    float s, c;
    __sincosf(0.5f * wt[41 + 3 * q], &s, &c);    // layer-1 theta_q
    grot1[q][0] = c;
    grot1[q][1] = s;
  } else if (tid < 232) {
    // layer-1 diagonal reg/axis tables: k bit0<->q3, bit1<->q2, bit2<->q1, axis<->q0
    const int t = tid - 200;
    const int dia = t >> 4;            // 0: phi (wt[40+3q]), 1: omega (wt[42+3q])
    const int u = t & 15;
    const int k = u & 7, ax = u >> 3;
    const int wb = dia ? 42 : 40;
    float ang = 0.0f;
    if (k & 1) ang += wt[wb + 9];
    if (k & 2) ang += wt[wb + 6];
    if (k & 4) ang += wt[wb + 3];
    if (ax)    ang += wt[wb + 0];
    float s, c;
    __sincosf(ang, &s, &c);
    float* gd = dia ? &gdome[0][0] : &gdphi[0][0];
    gd[k * 4 + ax]     = c;
    gd[k * 4 + 2 + ax] = s;
  }
  // second job: per-lane diag phase (lane bit p <-> qubit 9-p, p=0..5)
  if (tid < 128) {
    const int d = tid >> 6, ln = tid & 63;
    const int wb = d ? 42 : 40;
    float ang = 0.0f;
    if (ln & 1)  ang += wt[wb + 27];
    if (ln & 2)  ang += wt[wb + 24];
    if (ln & 4)  ang += wt[wb + 21];
    if (ln & 8)  ang += wt[wb + 18];
    if (ln & 16) ang += wt[wb + 15];
    if (ln & 32) ang += wt[wb + 12];
    float s, c;
    __sincosf(ang, &s, &c);
    gzlane[d][ln][0] = c;
    gzlane[d][ln][1] = s;
  }
  __syncthreads();

  // ---- setup phase 2 (needs gm and gtrig) ----
  for (int pr = tid; pr < 384; pr += 256) {
    const int p = pr >> 6, ln = pr & 63;
    const float* m = &gm[9 - p][0];
    const bool b = (ln >> p) & 1;
    growtab[p][ln][0] = b ? m[4] : m[0];
    growtab[p][ln][1] = b ? m[5] : m[1];
    growtab[p][ln][2] = b ? m[6] : m[2];
    growtab[p][ln][3] = b ? m[7] : m[3];
  }
  if (tid < 128) {
    // u-vectors for reg/axis bits: gmIdx g=0..3 <-> amp bit 9-g, trig bit p=9-g
    const int s = tid >> 3, g = (tid >> 1) & 3, b = tid & 1;
    const float* m = &gm[g][0];
    const float fcv = gtrig[s][9 - g][0], fsv = gtrig[s][9 - g][1];
    const float m0 = b ? m[4] : m[0], m1 = b ? m[5] : m[1];
    const float m2 = b ? m[6] : m[2], m3 = b ? m[7] : m[3];
    gutab[s][g][b][0] = m0 * fcv + m2 * fsv;
    gutab[s][g][b][1] = m1 * fcv + m3 * fsv;
  }
  __syncthreads();

  const int lane = tid & 63;
  const int bpa = (lane ^ 32) << 2;              // ds_bpermute byte address
  const int wave = tid >> 6;

#pragma unroll 1
  for (int j = 0; j < SPW; ++j) {
    const int s = wave * SPW + j;                // local sample 0..15
    const int gsample = base + s;
    if (gsample >= B) break;

    // ---- init: lane factor L = prod_{p=0..5} u_p[lane bit p] ----
    float Lr, Li;
    {
      const float2 t0 = *(const float2*)&gtrig[s][0][0];
      const float4 m0 = *(const float4*)&growtab[0][lane][0];
      Lr = m0.x * t0.x + m0.z * t0.y;
      Li = m0.y * t0.x + m0.w * t0.y;
    }
#pragma unroll
    for (int p = 1; p < 6; ++p) {
      const float2 tp = *(const float2*)&gtrig[s][p][0];
      const float4 mp = *(const float4*)&growtab[p][lane][0];
      const float ur = mp.x * tp.x + mp.z * tp.y;
      const float ui = mp.y * tp.x + mp.w * tp.y;
      cmul(Lr, Li, ur, ui);
    }

    // ---- register-factor tree A[k] = L * u6[k&1] * u7[(k>>1)&1] * u8[(k>>2)&1] ----
    float Ar[8], Ai[8];
    {
      const float2 u0 = *(const float2*)&gutab[s][3][0][0];   // amp bit 6
      const float2 u1 = *(const float2*)&gutab[s][3][1][0];
      Ar[0] = Lr*u0.x - Li*u0.y;  Ai[0] = Lr*u0.y + Li*u0.x;
      Ar[1] = Lr*u1.x - Li*u1.y;  Ai[1] = Lr*u1.y + Li*u1.x;
    }
    {
      const float2 u0 = *(const float2*)&gutab[s][2][0][0];   // amp bit 7
      const float2 u1 = *(const float2*)&gutab[s][2][1][0];
#pragma unroll
      for (int k = 0; k < 2; ++k) {
        Ar[k+2] = Ar[k]*u1.x - Ai[k]*u1.y;  Ai[k+2] = Ar[k]*u1.y + Ai[k]*u1.x;
        cmul(Ar[k], Ai[k], u0.x, u0.y);
      }
    }
    {
      const float2 u0 = *(const float2*)&gutab[s][1][0][0];   // amp bit 8
      const float2 u1 = *(const float2*)&gutab[s][1][1][0];
#pragma unroll
      for (int k = 0; k < 4; ++k) {
        Ar[k+4] = Ar[k]*u1.x - Ai[k]*u1.y;  Ai[k+4] = Ar[k]*u1.y + Ai[k]*u1.x;
        cmul(Ar[k], Ai[k], u0.x, u0.y);
      }
    }

    v2f Sr[8], Si[8];
    {
      const float2 u90 = *(const float2*)&gutab[s][0][0][0];  // amp bit 9 (axis)
      const float2 u91 = *(const float2*)&gutab[s][0][1][0];
      const v2f u9r = {u90.x, u91.x}, u9i = {u90.y, u91.y};
#pragma unroll
      for (int k = 0; k < 8; ++k) {
        Sr[k] = Ar[k]*u9r - Ai[k]*u9i;
        Si[k] = Ar[k]*u9i + Ai[k]*u9r;
      }
    }

    // ---- layer 0: CRY ring (Rot folded into init) ----
    {
      const float (*cc)[2] = &gc[0];
      cry_axisctrl        (Sr, Si, cc[0][0], cc[0][1]);              // (p9,p8)
      cry_reg_reg<4, 2>   (Sr, Si, cc[1][0], cc[1][1]);              // (p8,p7)
      cry_reg_reg<2, 1>   (Sr, Si, cc[2][0], cc[2][1]);              // (p7,p6)
      cry_k0ctrl_lane5    (Sr, Si, cc[3][0], cc[3][1], lane, bpa);   // (p6,p5)
      cry_lane_lane<5, 4> (Sr, Si, cc[4][0], cc[4][1], lane, bpa);
      cry_lane_lane<4, 3> (Sr, Si, cc[5][0], cc[5][1], lane, bpa);
      cry_lane_lane<3, 2> (Sr, Si, cc[6][0], cc[6][1], lane, bpa);
      cry_lane_lane<2, 1> (Sr, Si, cc[7][0], cc[7][1], lane, bpa);
      cry_lane_lane<1, 0> (Sr, Si, cc[8][0], cc[8][1], lane, bpa);
      cry_lanectrl_axis   (Sr, Si, cc[9][0], cc[9][1], lane);        // (p0,p9)
    }

    // ---- layer 1: D_phi -> real RY layer -> D_omega -> CRY ring ----
    {
      const float2 zp = *(const float2*)&gzlane[0][lane][0];
      apply_diag(Sr, Si, zp.x, zp.y, gdphi);
      ry_axis   (Sr, Si, grot1[0][0], grot1[0][1]);          // q=0, axis
      ry_reg<4> (Sr, Si, grot1[1][0], grot1[1][1]);          // q=1, amp bit 8
      ry_reg<2> (Sr, Si, grot1[2][0], grot1[2][1]);          // q=2, amp bit 7
      ry_reg<1> (Sr, Si, grot1[3][0], grot1[3][1]);          // q=3, amp bit 6
      ry_lane<5>(Sr, Si, grot1[4][0], grot1[4][1], lane, bpa);
      ry_lane<4>(Sr, Si, grot1[5][0], grot1[5][1], lane, bpa);
      ry_lane<3>(Sr, Si, grot1[6][0], grot1[6][1], lane, bpa);
      ry_lane<2>(Sr, Si, grot1[7][0], grot1[7][1], lane, bpa);
      ry_lane<1>(Sr, Si, grot1[8][0], grot1[8][1], lane, bpa);
      ry_lane<0>(Sr, Si, grot1[9][0], grot1[9][1], lane, bpa);
      const float2 zo = *(const float2*)&gzlane[1][lane][0];
      apply_diag(Sr, Si, zo.x, zo.y, gdome);

      const float (*cc)[2] = &gc[10];
      cry_axisctrl        (Sr, Si, cc[0][0], cc[0][1]);
      cry_reg_reg<4, 2>   (Sr, Si, cc[1][0], cc[1][1]);
      cry_reg_reg<2, 1>   (Sr, Si, cc[2][0], cc[2][1]);
      cry_k0ctrl_lane5    (Sr, Si, cc[3][0], cc[3][1], lane, bpa);
      cry_lane_lane<5, 4> (Sr, Si, cc[4][0], cc[4][1], lane, bpa);
      cry_lane_lane<4, 3> (Sr, Si, cc[5][0], cc[5][1], lane, bpa);
      cry_lane_lane<3, 2> (Sr, Si, cc[6][0], cc[6][1], lane, bpa);
      cry_lane_lane<2, 1> (Sr, Si, cc[7][0], cc[7][1], lane, bpa);
      cry_lane_lane<1, 0> (Sr, Si, cc[8][0], cc[8][1], lane, bpa);
      cry_lanectrl_axis   (Sr, Si, cc[9][0], cc[9][1], lane);
    }

    // ---- probabilities and PauliZ expvals ----
    v2f P[8];
#pragma unroll
    for (int k = 0; k < 8; ++k) P[k] = Sr[k]*Sr[k] + Si[k]*Si[k];

    const v2f q01 = P[0]+P[1], q23 = P[2]+P[3], q45 = P[4]+P[5], q67 = P[6]+P[7];
    const v2f h1 = q01+q23, h2 = q45+q67;
    const v2f t2 = h1 + h2;                           // per-lane total
    const v2f e8v = h1 - h2;                          // sign on amp bit 8
    const v2f e7v = (q01 - q23) + (q45 - q67);        // sign on amp bit 7
    const v2f d01 = P[0]-P[1], d23 = P[2]-P[3], d45 = P[4]-P[5], d67 = P[6]-P[7];
    const v2f e6v = (d01 + d23) + (d45 + d67);        // sign on amp bit 6

    const float tot = t2.x + t2.y;
    const float o6 = e6v.x + e6v.y;
    const float o7 = e7v.x + e7v.y;
    const float o8 = e8v.x + e8v.y;
    const float o9 = t2.x - t2.y;

    float sgn[6];
#pragma unroll
    for (int p = 0; p < 6; ++p) sgn[p] = ((lane >> p) & 1) ? -1.0f : 1.0f;

    float E[6];
    float t = tot;
#define QSTEP(P)                                             \
    {                                                        \
      const float pt = xorf<P>(t, bpa);                      \
      E[P] = sgn[P] * (t - pt);                              \
      t += pt;                                               \
      _Pragma("unroll")                                      \
      for (int jj = 0; jj < P; ++jj) E[jj] += xorf<P>(E[jj], bpa); \
    }
    QSTEP(0) QSTEP(1) QSTEP(2) QSTEP(3) QSTEP(4) QSTEP(5)
#undef QSTEP

    v2f q1; q1.x = o6; q1.y = o7;
    v2f q2; q2.x = o8; q2.y = o9;
#define RSTEP(P)                   \
    q1 += partner2<P>(q1, bpa);    \
    q2 += partner2<P>(q2, bpa);
    RSTEP(0) RSTEP(1) RSTEP(2) RSTEP(3) RSTEP(4) RSTEP(5)
#undef RSTEP

    // out[sample][q], q = 9 - p:  q=0..3 <- bits 9,8,7,6 ; q=4..9 <- E[5..0]
    if (lane < 10) {
      float v = q2.y;                  // q=0: bit 9
      v = (lane == 1) ? q2.x : v;      // bit 8
      v = (lane == 2) ? q1.y : v;      // bit 7
      v = (lane == 3) ? q1.x : v;      // bit 6
      v = (lane == 4) ? E[5] : v;
      v = (lane == 5) ? E[4] : v;
      v = (lane == 6) ? E[3] : v;
      v = (lane == 7) ? E[2] : v;
      v = (lane == 8) ? E[1] : v;
      v = (lane == 9) ? E[0] : v;
      out[gsample * NQB + lane] = v;
    }
  }
}

extern "C" void kernel_launch(void* const* d_in, const int* in_sizes, int n_in,
                              void* d_out, int out_size, void* d_ws, size_t ws_size,
                              hipStream_t stream) {
  const float* inp = (const float*)d_in[0];
  const float* wt  = (const float*)d_in[1];
  float* out = (float*)d_out;
  const int B = in_sizes[0] / NQB;            // 32768
  const int nblocks = (B + SPB - 1) / SPB;    // 2048
  hipLaunchKernelGGL(qlayer_kernel, dim3(nblocks), dim3(256), 0, stream,
                     inp, wt, out, B);
}